// Round 1
// baseline (551.188 us; speedup 1.0000x reference)
//
#include <hip/hip_runtime.h>
#include <cstdint>
#include <cstddef>

#define BB 64
#define NN 8192
#define MM 128
#define LOG2N 13

// ---------------- Kernel A: logits[b,n] = beta[b] * cosine(memory[b,n,:]+eps, k[b,:]+eps)
// One wave (64 lanes) per row; each lane holds 2 consecutive floats (float2).
__global__ __launch_bounds__(256) void score_kernel(const float* __restrict__ memory,
                                                    const float* __restrict__ k,
                                                    const float* __restrict__ beta,
                                                    float* __restrict__ logits) {
    const int wave   = (blockIdx.x * blockDim.x + threadIdx.x) >> 6;
    const int lane   = threadIdx.x & 63;
    const int nwaves = (gridDim.x * blockDim.x) >> 6;
    const int total  = BB * NN;
    for (int row = wave; row < total; row += nwaves) {
        const int b = row >> LOG2N;
        const float2 mv_raw = ((const float2*)(memory + (size_t)row * MM))[lane];
        const float2 kv_raw = ((const float2*)(k + b * MM))[lane];
        float mx = mv_raw.x + 1e-16f, my = mv_raw.y + 1e-16f;
        float kx = kv_raw.x + 1e-16f, ky = kv_raw.y + 1e-16f;
        float dot = mx * kx + my * ky;
        float nm2 = mx * mx + my * my;
        float nk2 = kx * kx + ky * ky;
        #pragma unroll
        for (int o = 32; o > 0; o >>= 1) {
            dot += __shfl_xor(dot, o, 64);
            nm2 += __shfl_xor(nm2, o, 64);
            nk2 += __shfl_xor(nk2, o, 64);
        }
        if (lane == 0) {
            float nm = fmaxf(sqrtf(nm2), 1e-8f);
            float nk = fmaxf(sqrtf(nk2), 1e-8f);
            logits[row] = beta[b] * dot / (nm * nk);
        }
    }
}

// ---------------- Kernel B: softmax over N + interpolation + circular shift + sharpen + renorm
// One block (1024 threads) per batch. wg staged in LDS for the shift.
__global__ __launch_bounds__(1024) void weight_kernel(const float* __restrict__ logits,
                                                      const float* __restrict__ g,
                                                      const float* __restrict__ s,
                                                      const float* __restrict__ gamma,
                                                      const float* __restrict__ w_prev,
                                                      float* __restrict__ wout) {
    __shared__ float wgs[NN];
    __shared__ float red[16];
    __shared__ float bcast;
    const int b   = blockIdx.x;
    const int tid = threadIdx.x;
    const float* lrow = logits + (size_t)b * NN;

    // --- load 8 logits/thread, block max ---
    float l[8];
    float mx = -1e30f;
    #pragma unroll
    for (int j = 0; j < 8; j++) {
        l[j] = lrow[tid + j * 1024];
        mx = fmaxf(mx, l[j]);
    }
    #pragma unroll
    for (int o = 32; o > 0; o >>= 1) mx = fmaxf(mx, __shfl_xor(mx, o, 64));
    if ((tid & 63) == 0) red[tid >> 6] = mx;
    __syncthreads();
    if (tid < 64) {
        float x = (tid < 16) ? red[tid] : -1e30f;
        #pragma unroll
        for (int o = 8; o > 0; o >>= 1) x = fmaxf(x, __shfl_xor(x, o, 64));
        if (tid == 0) bcast = x;
    }
    __syncthreads();
    mx = bcast;

    // --- exp + block sum ---
    float se = 0.f;
    #pragma unroll
    for (int j = 0; j < 8; j++) { l[j] = expf(l[j] - mx); se += l[j]; }
    #pragma unroll
    for (int o = 32; o > 0; o >>= 1) se += __shfl_xor(se, o, 64);
    __syncthreads();                      // protect red from previous use
    if ((tid & 63) == 0) red[tid >> 6] = se;
    __syncthreads();
    if (tid < 64) {
        float x = (tid < 16) ? red[tid] : 0.f;
        #pragma unroll
        for (int o = 8; o > 0; o >>= 1) x += __shfl_xor(x, o, 64);
        if (tid == 0) bcast = x;
    }
    __syncthreads();
    const float inv_se = 1.f / bcast;

    // --- interpolate, stage wg in LDS ---
    const float gv = g[b];
    const float one_m_g = 1.f - gv;
    const float* wp = w_prev + (size_t)b * NN;
    #pragma unroll
    for (int j = 0; j < 8; j++) {
        const int i = tid + j * 1024;
        wgs[i] = gv * (l[j] * inv_se) + one_m_g * wp[i];
    }
    __syncthreads();

    // --- circular shift + sharpen + block sum ---
    const float s0 = s[b * 3 + 0], s1 = s[b * 3 + 1], s2 = s[b * 3 + 2];
    const float gam = gamma[b];
    float w[8];
    float sw = 0.f;
    #pragma unroll
    for (int j = 0; j < 8; j++) {
        const int i = tid + j * 1024;
        const float wh = s0 * wgs[(i - 1) & (NN - 1)] + s1 * wgs[i] + s2 * wgs[(i + 1) & (NN - 1)];
        w[j] = powf(wh, gam);
        sw += w[j];
    }
    #pragma unroll
    for (int o = 32; o > 0; o >>= 1) sw += __shfl_xor(sw, o, 64);
    __syncthreads();
    if ((tid & 63) == 0) red[tid >> 6] = sw;
    __syncthreads();
    if (tid < 64) {
        float x = (tid < 16) ? red[tid] : 0.f;
        #pragma unroll
        for (int o = 8; o > 0; o >>= 1) x += __shfl_xor(x, o, 64);
        if (tid == 0) bcast = x;
    }
    __syncthreads();
    const float invt = 1.f / (bcast + 1e-16f);
    float* wo = wout + (size_t)b * NN;
    #pragma unroll
    for (int j = 0; j < 8; j++) wo[tid + j * 1024] = w[j] * invt;
}

// ---------------- Kernel C: r[b,m] = sum_n w*mem ; new_mem = mem*(1 - w*e) + w*a
// CHUNKS blocks per batch; 256 threads: 32 col-groups (float4) x 8 rows per iteration.
#define CHUNKS 16
__global__ __launch_bounds__(256) void update_kernel(const float* __restrict__ memory,
                                                     const float* __restrict__ w,
                                                     const float* __restrict__ e,
                                                     const float* __restrict__ a,
                                                     float* __restrict__ r,
                                                     float* __restrict__ nmem) {
    const int b     = blockIdx.x / CHUNKS;
    const int chunk = blockIdx.x % CHUNKS;
    const int rows  = NN / CHUNKS;          // 512
    const int n0    = chunk * rows;
    const int tid   = threadIdx.x;
    const int c4    = tid & 31;             // which float4 column group
    const int rg    = tid >> 5;             // row offset within a group of 8

    const float4 e4 = ((const float4*)(e + b * MM))[c4];
    const float4 a4 = ((const float4*)(a + b * MM))[c4];
    const float* wb = w + (size_t)b * NN + n0;
    const size_t base = ((size_t)b * NN + n0) * MM;
    const float4* min4 = (const float4*)(memory + base);
    float4* mout4      = (float4*)(nmem + base);

    float4 acc = make_float4(0.f, 0.f, 0.f, 0.f);
    for (int it = 0; it < rows; it += 8) {
        const int rr = it + rg;
        const float wv = wb[rr];
        const int idx = rr * 32 + c4;
        const float4 m4 = min4[idx];
        acc.x += wv * m4.x; acc.y += wv * m4.y; acc.z += wv * m4.z; acc.w += wv * m4.w;
        float4 o4;
        o4.x = m4.x * (1.f - wv * e4.x) + wv * a4.x;
        o4.y = m4.y * (1.f - wv * e4.y) + wv * a4.y;
        o4.z = m4.z * (1.f - wv * e4.z) + wv * a4.z;
        o4.w = m4.w * (1.f - wv * e4.w) + wv * a4.w;
        mout4[idx] = o4;
    }

    __shared__ float4 sred[256];
    sred[tid] = acc;
    __syncthreads();
    if (tid < 32) {
        float4 t = sred[tid];
        #pragma unroll
        for (int j = 1; j < 8; j++) {
            const float4 u = sred[tid + j * 32];
            t.x += u.x; t.y += u.y; t.z += u.z; t.w += u.w;
        }
        float* rp = r + b * MM + tid * 4;
        atomicAdd(rp + 0, t.x);
        atomicAdd(rp + 1, t.y);
        atomicAdd(rp + 2, t.z);
        atomicAdd(rp + 3, t.w);
    }
}

extern "C" void kernel_launch(void* const* d_in, const int* in_sizes, int n_in,
                              void* d_out, int out_size, void* d_ws, size_t ws_size,
                              hipStream_t stream) {
    const float* memory = (const float*)d_in[0];
    const float* k      = (const float*)d_in[1];
    const float* beta   = (const float*)d_in[2];
    const float* g      = (const float*)d_in[3];
    const float* s      = (const float*)d_in[4];
    const float* gamma  = (const float*)d_in[5];
    const float* w_prev = (const float*)d_in[6];
    const float* e      = (const float*)d_in[7];
    const float* a      = (const float*)d_in[8];

    float* out   = (float*)d_out;
    float* r     = out;                 // [B, M]
    float* nmem  = out + BB * MM;       // [B, N, M]
    float* logits = (float*)d_ws;       // [B, N]
    float* wfin   = logits + (size_t)BB * NN;  // [B, N]

    hipMemsetAsync(r, 0, BB * MM * sizeof(float), stream);
    score_kernel<<<2048, 256, 0, stream>>>(memory, k, beta, logits);
    weight_kernel<<<BB, 1024, 0, stream>>>(logits, g, s, gamma, w_prev, wfin);
    update_kernel<<<BB * CHUNKS, 256, 0, stream>>>(memory, wfin, e, a, r, nmem);
}

// Round 2
// 512.119 us; speedup vs baseline: 1.0763x; 1.0763x over previous
//
#include <hip/hip_runtime.h>
#include <cstdint>
#include <cstddef>

#define BB 64
#define NN 8192
#define MM 128
#define LOG2N 13

// ---------------- Kernel A v2: logits[b,n] = beta[b] * cosine(memory[b,n,:]+eps, k[b,:]+eps)
// 8192 waves total, 128 waves per batch, 64 consecutive rows per wave.
// Each lane loads a float4 (16B): one wave-load covers 2 rows (lanes 0-31 = row r,
// lanes 32-63 = row r+1). Butterfly reduction is 5 levels within each 32-lane half.
__global__ __launch_bounds__(256) void score_kernel(const float* __restrict__ memory,
                                                    const float* __restrict__ k,
                                                    const float* __restrict__ beta,
                                                    float* __restrict__ logits) {
    const int gw   = (blockIdx.x * 256 + threadIdx.x) >> 6;  // 0..8191
    const int lane = threadIdx.x & 63;
    const int b    = gw >> 7;          // 128 waves per batch
    const int ws   = gw & 127;
    const int l32  = lane & 31;
    const int half = lane >> 5;

    // per-batch constants (hoisted out of the row loop)
    float4 kv = ((const float4*)(k + b * MM))[l32];
    kv.x += 1e-16f; kv.y += 1e-16f; kv.z += 1e-16f; kv.w += 1e-16f;
    float nk2 = kv.x * kv.x + kv.y * kv.y + kv.z * kv.z + kv.w * kv.w;
    #pragma unroll
    for (int o = 1; o < 32; o <<= 1) nk2 += __shfl_xor(nk2, o, 64);
    const float sb = beta[b] / fmaxf(sqrtf(nk2), 1e-8f);

    const int row0 = ws * 64;                       // 64 rows per wave
    const float4* mp = (const float4*)(memory + ((size_t)b * NN + row0) * MM);
    float* lout = logits + (size_t)b * NN + row0;

    #pragma unroll 2
    for (int it = 0; it < 32; ++it) {               // 2 rows per iteration
        float4 m = mp[it * 64 + lane];
        m.x += 1e-16f; m.y += 1e-16f; m.z += 1e-16f; m.w += 1e-16f;
        float pdot = m.x * kv.x + m.y * kv.y + m.z * kv.z + m.w * kv.w;
        float pnm  = m.x * m.x + m.y * m.y + m.z * m.z + m.w * m.w;
        #pragma unroll
        for (int o = 1; o < 32; o <<= 1) {
            pdot += __shfl_xor(pdot, o, 64);
            pnm  += __shfl_xor(pnm,  o, 64);
        }
        if (l32 == 0) {
            lout[it * 2 + half] = sb * pdot / fmaxf(sqrtf(pnm), 1e-8f);
        }
    }
}

// ---------------- Kernel B: softmax over N + interpolation + circular shift + sharpen + renorm
// One block (1024 threads) per batch. wg staged in LDS for the shift.
__global__ __launch_bounds__(1024) void weight_kernel(const float* __restrict__ logits,
                                                      const float* __restrict__ g,
                                                      const float* __restrict__ s,
                                                      const float* __restrict__ gamma,
                                                      const float* __restrict__ w_prev,
                                                      float* __restrict__ wout) {
    __shared__ float wgs[NN];
    __shared__ float red[16];
    __shared__ float bcast;
    const int b   = blockIdx.x;
    const int tid = threadIdx.x;
    const float* lrow = logits + (size_t)b * NN;

    // --- load 8 logits/thread, block max ---
    float l[8];
    float mx = -1e30f;
    #pragma unroll
    for (int j = 0; j < 8; j++) {
        l[j] = lrow[tid + j * 1024];
        mx = fmaxf(mx, l[j]);
    }
    #pragma unroll
    for (int o = 32; o > 0; o >>= 1) mx = fmaxf(mx, __shfl_xor(mx, o, 64));
    if ((tid & 63) == 0) red[tid >> 6] = mx;
    __syncthreads();
    if (tid < 64) {
        float x = (tid < 16) ? red[tid] : -1e30f;
        #pragma unroll
        for (int o = 8; o > 0; o >>= 1) x = fmaxf(x, __shfl_xor(x, o, 64));
        if (tid == 0) bcast = x;
    }
    __syncthreads();
    mx = bcast;

    // --- exp + block sum ---
    float se = 0.f;
    #pragma unroll
    for (int j = 0; j < 8; j++) { l[j] = __expf(l[j] - mx); se += l[j]; }
    #pragma unroll
    for (int o = 32; o > 0; o >>= 1) se += __shfl_xor(se, o, 64);
    __syncthreads();
    if ((tid & 63) == 0) red[tid >> 6] = se;
    __syncthreads();
    if (tid < 64) {
        float x = (tid < 16) ? red[tid] : 0.f;
        #pragma unroll
        for (int o = 8; o > 0; o >>= 1) x += __shfl_xor(x, o, 64);
        if (tid == 0) bcast = x;
    }
    __syncthreads();
    const float inv_se = 1.f / bcast;

    // --- interpolate, stage wg in LDS ---
    const float gv = g[b];
    const float one_m_g = 1.f - gv;
    const float* wp = w_prev + (size_t)b * NN;
    #pragma unroll
    for (int j = 0; j < 8; j++) {
        const int i = tid + j * 1024;
        wgs[i] = gv * (l[j] * inv_se) + one_m_g * wp[i];
    }
    __syncthreads();

    // --- circular shift + sharpen + block sum ---
    const float s0 = s[b * 3 + 0], s1 = s[b * 3 + 1], s2 = s[b * 3 + 2];
    const float gam = gamma[b];
    float w[8];
    float sw = 0.f;
    #pragma unroll
    for (int j = 0; j < 8; j++) {
        const int i = tid + j * 1024;
        const float wh = s0 * wgs[(i - 1) & (NN - 1)] + s1 * wgs[i] + s2 * wgs[(i + 1) & (NN - 1)];
        w[j] = __expf(gam * __logf(wh));   // wh > 0 guaranteed (g<1, w_prev>0, softmax>0)
        sw += w[j];
    }
    #pragma unroll
    for (int o = 32; o > 0; o >>= 1) sw += __shfl_xor(sw, o, 64);
    __syncthreads();
    if ((tid & 63) == 0) red[tid >> 6] = sw;
    __syncthreads();
    if (tid < 64) {
        float x = (tid < 16) ? red[tid] : 0.f;
        #pragma unroll
        for (int o = 8; o > 0; o >>= 1) x += __shfl_xor(x, o, 64);
        if (tid == 0) bcast = x;
    }
    __syncthreads();
    const float invt = 1.f / (bcast + 1e-16f);
    float* wo = wout + (size_t)b * NN;
    #pragma unroll
    for (int j = 0; j < 8; j++) wo[tid + j * 1024] = w[j] * invt;
}

// ---------------- Kernel C: r[b,m] = sum_n w*mem ; new_mem = mem*(1 - w*e) + w*a
// CHUNKS blocks per batch; 256 threads: 32 col-groups (float4) x 8 rows per iteration.
#define CHUNKS 32
__global__ __launch_bounds__(256) void update_kernel(const float* __restrict__ memory,
                                                     const float* __restrict__ w,
                                                     const float* __restrict__ e,
                                                     const float* __restrict__ a,
                                                     float* __restrict__ r,
                                                     float* __restrict__ nmem) {
    const int b     = blockIdx.x / CHUNKS;
    const int chunk = blockIdx.x % CHUNKS;
    const int rows  = NN / CHUNKS;          // 256
    const int n0    = chunk * rows;
    const int tid   = threadIdx.x;
    const int c4    = tid & 31;             // which float4 column group
    const int rg    = tid >> 5;             // row offset within a group of 8

    const float4 e4 = ((const float4*)(e + b * MM))[c4];
    const float4 a4 = ((const float4*)(a + b * MM))[c4];
    const float* wb = w + (size_t)b * NN + n0;
    const size_t base = ((size_t)b * NN + n0) * MM;
    const float4* min4 = (const float4*)(memory + base);
    float4* mout4      = (float4*)(nmem + base);

    float4 acc = make_float4(0.f, 0.f, 0.f, 0.f);
    #pragma unroll 2
    for (int it = 0; it < rows; it += 8) {
        const int rr = it + rg;
        const float wv = wb[rr];
        const int idx = rr * 32 + c4;
        const float4 m4 = min4[idx];
        acc.x += wv * m4.x; acc.y += wv * m4.y; acc.z += wv * m4.z; acc.w += wv * m4.w;
        float4 o4;
        o4.x = m4.x * (1.f - wv * e4.x) + wv * a4.x;
        o4.y = m4.y * (1.f - wv * e4.y) + wv * a4.y;
        o4.z = m4.z * (1.f - wv * e4.z) + wv * a4.z;
        o4.w = m4.w * (1.f - wv * e4.w) + wv * a4.w;
        mout4[idx] = o4;
    }

    __shared__ float4 sred[256];
    sred[tid] = acc;
    __syncthreads();
    if (tid < 32) {
        float4 t = sred[tid];
        #pragma unroll
        for (int j = 1; j < 8; j++) {
            const float4 u = sred[tid + j * 32];
            t.x += u.x; t.y += u.y; t.z += u.z; t.w += u.w;
        }
        float* rp = r + b * MM + tid * 4;
        atomicAdd(rp + 0, t.x);
        atomicAdd(rp + 1, t.y);
        atomicAdd(rp + 2, t.z);
        atomicAdd(rp + 3, t.w);
    }
}

extern "C" void kernel_launch(void* const* d_in, const int* in_sizes, int n_in,
                              void* d_out, int out_size, void* d_ws, size_t ws_size,
                              hipStream_t stream) {
    const float* memory = (const float*)d_in[0];
    const float* k      = (const float*)d_in[1];
    const float* beta   = (const float*)d_in[2];
    const float* g      = (const float*)d_in[3];
    const float* s      = (const float*)d_in[4];
    const float* gamma  = (const float*)d_in[5];
    const float* w_prev = (const float*)d_in[6];
    const float* e      = (const float*)d_in[7];
    const float* a      = (const float*)d_in[8];

    float* out   = (float*)d_out;
    float* r     = out;                 // [B, M]
    float* nmem  = out + BB * MM;       // [B, N, M]
    float* logits = (float*)d_ws;       // [B, N]
    float* wfin   = logits + (size_t)BB * NN;  // [B, N]

    hipMemsetAsync(r, 0, BB * MM * sizeof(float), stream);
    score_kernel<<<2048, 256, 0, stream>>>(memory, k, beta, logits);
    weight_kernel<<<BB, 1024, 0, stream>>>(logits, g, s, gamma, w_prev, wfin);
    update_kernel<<<BB * CHUNKS, 256, 0, stream>>>(memory, wfin, e, a, r, nmem);
}